// Round 5
// baseline (2128.973 us; speedup 1.0000x reference)
//
#include <hip/hip_runtime.h>

// DFPS: density-weighted Manhattan furthest point sampling.
// points:   [B, N, 3] f32   (B=4, N=8192 fixed by the problem)
// features: [B, C, N] f32   (unused)
// npoint:   int scalar (device, d_in[2])
// out:      [B, npoint] int32 indices

#define NPTS 8192
#define DENS_BLOCK 256
#define DENS_SPLIT 4
#define FPS_THREADS 512
#define FPS_P 16   // FPS_THREADS * FPS_P == NPTS
#define FPS_P2 (FPS_P / 2)

typedef float v2f __attribute__((ext_vector_type(2)));

// ---------------- density ----------------
// j-coords are wave-uniform -> scalar loads, no LDS, no barriers.
// Each block covers 2048 j's (split 4); partial counts go to separate planes.

__global__ void dfps_density_partial(const float* __restrict__ pts,
                                     float* __restrict__ pen4, int N) {
#pragma clang fp contract(off)
    const float R2 = (float)(0.4 * 0.4);  // matches JAX scalar promotion
    const int b = blockIdx.y;
    const int z = blockIdx.z;
    const int i = blockIdx.x * blockDim.x + threadIdx.x;
    const float* P = pts + (size_t)b * N * 3;

    const v2f px2 = {P[i * 3 + 0], P[i * 3 + 0]};
    const v2f py2 = {P[i * 3 + 1], P[i * 3 + 1]};
    const v2f pz2 = {P[i * 3 + 2], P[i * 3 + 2]};

    const int j0 = z * (N / DENS_SPLIT);
    const int j1 = j0 + (N / DENS_SPLIT);

    int cnt = 0;
#pragma unroll 4
    for (int j = j0; j < j1; j += 2) {
        // uniform addresses -> s_load; pairs packed for v_pk_{add,mul}_f32
        v2f qx = {P[3 * j + 0], P[3 * j + 3]};
        v2f qy = {P[3 * j + 1], P[3 * j + 4]};
        v2f qz = {P[3 * j + 2], P[3 * j + 5]};
        v2f dx = px2 - qx;
        v2f dy = py2 - qy;
        v2f dz = pz2 - qz;
        v2f d2 = dx * dx;       // contract(off): numpy mul-then-add rounding
        d2 = d2 + dy * dy;
        d2 = d2 + dz * dz;
        cnt += (d2.x <= R2) ? 1 : 0;
        cnt += (d2.y <= R2) ? 1 : 0;
    }
    pen4[(size_t)(z * 4 + b) * N + i] = (float)cnt;  // exact small-int float
}

// ---------------- FPS ----------------

// u64 max across the 64-lane wave via DPP (VALU pipe, no LDS round-trips).
// Result valid in lane 63.
#define DPP_STEP(ctrl, rmask)                                                   \
    {                                                                           \
        unsigned int nlo = (unsigned int)__builtin_amdgcn_update_dpp(           \
            0, (int)klo, (ctrl), (rmask), 0xF, false);                          \
        unsigned int nhi = (unsigned int)__builtin_amdgcn_update_dpp(           \
            0, (int)khi, (ctrl), (rmask), 0xF, false);                          \
        unsigned long long o = ((unsigned long long)nhi << 32) | nlo;           \
        unsigned long long c = ((unsigned long long)khi << 32) | klo;           \
        if (o > c) { klo = nlo; khi = nhi; }                                    \
    }

__global__ void __launch_bounds__(FPS_THREADS, 1)
dfps_fps_kernel(const float* __restrict__ pts,
                const float* __restrict__ pen4,
                const int* __restrict__ npoint_p,
                int* __restrict__ out, int N) {
#pragma clang fp contract(off)
    const int b = blockIdx.x;
    const int tid = threadIdx.x;
    const int lane = tid & 63;
    const int npoint = *npoint_p;
    const float* Pb = pts + (size_t)b * N * 3;
    const int base = tid * FPS_P;

    // Coordinate table in LDS (float4) -> one b128 winner fetch.
    __shared__ float4 tab[NPTS];                 // 128 KiB
    // Triple-buffered block-winner slot (ds_max_u64); every conflicting
    // access pair is separated by at least one __syncthreads() (see R3).
    __shared__ unsigned long long slot[3];

    // Per-thread state: point-pairs packed in float2 for v_pk ops.
    v2f xp[FPS_P2], yp[FPS_P2], zp[FPS_P2], mdp[FPS_P2], pwp[FPS_P2];
    unsigned int lo[FPS_P];  // key low words: N-1-idx (min-idx tiebreak)
#pragma unroll
    for (int j = 0; j < FPS_P2; ++j) {
        int idx = base + 2 * j;
        float x0 = Pb[idx * 3 + 0], y0 = Pb[idx * 3 + 1], z0 = Pb[idx * 3 + 2];
        float x1 = Pb[idx * 3 + 3], y1 = Pb[idx * 3 + 4], z1 = Pb[idx * 3 + 5];
        xp[j] = (v2f){x0, x1};
        yp[j] = (v2f){y0, y1};
        zp[j] = (v2f){z0, z1};
        mdp[j] = (v2f){1e10f, 1e10f};
        // penalty = 1 / (sum of 4 exact-integer partial counts)
        float c0 = pen4[(size_t)(0 * 4 + b) * N + idx]     + pen4[(size_t)(1 * 4 + b) * N + idx];
        float c1 = pen4[(size_t)(2 * 4 + b) * N + idx]     + pen4[(size_t)(3 * 4 + b) * N + idx];
        float e0 = pen4[(size_t)(0 * 4 + b) * N + idx + 1] + pen4[(size_t)(1 * 4 + b) * N + idx + 1];
        float e1 = pen4[(size_t)(2 * 4 + b) * N + idx + 1] + pen4[(size_t)(3 * 4 + b) * N + idx + 1];
        pwp[j] = (v2f){1.0f / (c0 + c1), 1.0f / (e0 + e1)};
        lo[2 * j]     = (unsigned int)(N - 1 - idx);
        lo[2 * j + 1] = (unsigned int)(N - 1 - (idx + 1));
        tab[idx]     = make_float4(x0, y0, z0, 0.f);
        tab[idx + 1] = make_float4(x1, y1, z1, 0.f);
    }
    if (tid == 0) { slot[0] = 0ull; slot[2] = 0ull; }  // slot[1] zeroed in body 0
    __syncthreads();

    int cur = 0;
    float cx = Pb[0], cy = Pb[1], cz = Pb[2];

    for (int t = 0; t < npoint; ++t) {
        // Singleton work on different waves to reduce barrier skew.
        if (tid == 64) out[(size_t)b * npoint + t] = cur;
        if (tid == 128) slot[(t + 1) % 3] = 0ull;

        const v2f cx2 = {cx, cx}, cy2 = {cy, cy}, cz2 = {cz, cz};

        // Distance update + u64 argmax keys; 4 chains for ILP.
        unsigned long long ck0 = 0ull, ck1 = 0ull, ck2 = 0ull, ck3 = 0ull;
#pragma unroll
        for (int j = 0; j < FPS_P2; ++j) {
            v2f dx = xp[j] - cx2;   // v_pk_add_f32 (neg)
            v2f dy = yp[j] - cy2;
            v2f dz = zp[j] - cz2;
            // w=[1,1,2]; abs folds into VOP3 modifiers on add/fma;
            // fmaf(2,|dz|,s) == s + 2*|dz| bitwise (2*|dz| exact)
            float d0 = fabsf(dx.x) + fabsf(dy.x);
            float d1 = fabsf(dx.y) + fabsf(dy.y);
            d0 = fmaf(2.0f, fabsf(dz.x), d0);
            d1 = fmaf(2.0f, fabsf(dz.y), d1);
            v2f m;
            m.x = fminf(mdp[j].x, d0);
            m.y = fminf(mdp[j].y, d1);
            mdp[j] = m;
            v2f v = m * pwp[j];     // v_pk_mul_f32; v >= 0 -> bit order == uint
            unsigned long long k0 =
                ((unsigned long long)__float_as_uint(v.x) << 32) | lo[2 * j];
            unsigned long long k1 =
                ((unsigned long long)__float_as_uint(v.y) << 32) | lo[2 * j + 1];
            if (j & 1) {
                if (k0 > ck2) ck2 = k0;
                if (k1 > ck3) ck3 = k1;
            } else {
                if (k0 > ck0) ck0 = k0;
                if (k1 > ck1) ck1 = k1;
            }
        }
        unsigned long long ka = ck0 > ck1 ? ck0 : ck1;
        unsigned long long kb = ck2 > ck3 ? ck2 : ck3;
        unsigned long long best = ka > kb ? ka : kb;

        // Wave64 u64 max via DPP: row_shr 1/2/4/8, then row_bcast 15/31.
        unsigned int klo = (unsigned int)best;
        unsigned int khi = (unsigned int)(best >> 32);
        DPP_STEP(0x111, 0xF)  // row_shr:1
        DPP_STEP(0x112, 0xF)  // row_shr:2
        DPP_STEP(0x114, 0xF)  // row_shr:4
        DPP_STEP(0x118, 0xF)  // row_shr:8
        DPP_STEP(0x142, 0xA)  // row_bcast:15 -> rows 1,3
        DPP_STEP(0x143, 0xC)  // row_bcast:31 -> rows 2,3

        if (lane == 63) {
            unsigned long long wk = ((unsigned long long)khi << 32) | klo;
            atomicMax(&slot[t % 3], wk);  // ds_max_u64
        }
        __syncthreads();  // single barrier per iteration

        unsigned long long bk = slot[t % 3];
        cur = (N - 1) - (int)(unsigned int)(bk & 0xFFFFFFFFull);
        float4 c = tab[cur];  // uniform address -> LDS broadcast read
        cx = c.x;
        cy = c.y;
        cz = c.z;
    }
}

extern "C" void kernel_launch(void* const* d_in, const int* in_sizes, int n_in,
                              void* d_out, int out_size, void* d_ws, size_t ws_size,
                              hipStream_t stream) {
    const float* points  = (const float*)d_in[0];
    const int*   npoint  = (const int*)d_in[2];
    int* out = (int*)d_out;

    const int B = 4;
    const int N = in_sizes[0] / (B * 3);  // 8192
    float* pen4 = (float*)d_ws;           // DENS_SPLIT * B * N floats = 512 KiB

    dim3 dgrid(N / DENS_BLOCK, B, DENS_SPLIT);
    dfps_density_partial<<<dgrid, DENS_BLOCK, 0, stream>>>(points, pen4, N);

    dfps_fps_kernel<<<B, FPS_THREADS, 0, stream>>>(points, pen4, npoint, out, N);
}